// Round 4
// baseline (195.254 us; speedup 1.0000x reference)
//
#include <hip/hip_runtime.h>

// DotAttentionLayer: q,k,v are [B,N] (B=16, N=4096). Head dim == 1:
//   dist[b,i,j] = softmax_j(q[b,i]*k[b,j]/64); out[b,i] = sum_j dist*v[b,j]
// d_out = [ output (B*N f32) | distribution (B*N*N f32) ] ~1.07 GB writes ->
// write-BW-bound (fill-rate floor ~164 us at 6.56 TB/s).
//
// R4: one WAVE per row (was: one 4-wave block + LDS barrier reduce).
// Each wave holds its row's 16 f32x4 exp values in registers, butterfly
// shfl_xor all-reduce (no LDS, no __syncthreads), then streams nt stores
// immediately -- removes the block-wide pre-store convoy.

typedef float f32x4 __attribute__((ext_vector_type(4)));

constexpr int kThreads = 256;                 // 4 waves/block, 1 row/wave
constexpr int kWavesPerBlock = kThreads / 64;
constexpr int kIter = 16;                     // N/4/64 = 4096/256 (shape fixed)
constexpr float kInvSqrtScale = 1.0f / 64.0f; // 1/sqrt(4096)

__device__ __forceinline__ float wave_allreduce_sum(float x) {
#pragma unroll
  for (int m = 1; m < 64; m <<= 1) x += __shfl_xor(x, m, 64);
  return x;
}

__global__ __launch_bounds__(kThreads) void dot_attn_wave_kernel(
    const float* __restrict__ q, const float* __restrict__ k,
    const float* __restrict__ v, float* __restrict__ out,
    float* __restrict__ dist, int N) {
  const int lane = threadIdx.x & 63;
  const int wid = threadIdx.x >> 6;
  const int row = blockIdx.x * kWavesPerBlock + wid;  // row = b*N + i
  const int b = row / N;
  const float a = q[row] * kInvSqrtScale;

  const int nf4 = N / 4;  // 1024 float4 per row
  const f32x4* kb = reinterpret_cast<const f32x4*>(k) + (size_t)b * nf4;
  const f32x4* vb = reinterpret_cast<const f32x4*>(v) + (size_t)b * nf4;

  // 16 f32x4 per lane at stride 64 (each wave load/store inst = 1 KB line-
  // aligned contiguous). e[] fully static-indexed -> stays in VGPRs.
  f32x4 e[kIter];
  float s = 0.f, pv = 0.f;
#pragma unroll
  for (int t = 0; t < kIter; ++t) {
    const int idx = t * 64 + lane;
    const f32x4 kk = kb[idx];
    const f32x4 vv = vb[idx];
    f32x4 ee;
    ee.x = __expf(a * kk.x);
    ee.y = __expf(a * kk.y);
    ee.z = __expf(a * kk.z);
    ee.w = __expf(a * kk.w);
    e[t] = ee;
    s  += (ee.x + ee.y) + (ee.z + ee.w);
    pv += (ee.x * vv.x + ee.y * vv.y) + (ee.z * vv.z + ee.w * vv.w);
  }

  // Wave-local butterfly all-reduce: no LDS, no barrier, all lanes get sums.
  s = wave_allreduce_sum(s);
  pv = wave_allreduce_sum(pv);
  const float rinv = 1.0f / s;

  f32x4* drow = reinterpret_cast<f32x4*>(dist) + (size_t)row * nf4;
#pragma unroll
  for (int t = 0; t < kIter; ++t) {
    const int idx = t * 64 + lane;
    const f32x4 dd = e[t] * rinv;
    __builtin_nontemporal_store(dd, &drow[idx]);  // 1 GB stream: no-allocate
  }

  if (lane == 0) out[row] = pv * rinv;
}

extern "C" void kernel_launch(void* const* d_in, const int* in_sizes, int n_in,
                              void* d_out, int out_size, void* d_ws, size_t ws_size,
                              hipStream_t stream) {
  // setup_inputs dict order: query, value, key  (f32 each, [B,N])
  const float* q = (const float*)d_in[0];
  const float* v = (const float*)d_in[1];
  const float* k = (const float*)d_in[2];

  const int S = in_sizes[0];                      // B*N = 65536 rows
  const int N = (int)((size_t)out_size / S) - 1;  // 4096
  float* out = (float*)d_out;                     // [B*N]
  float* dist = out + S;                          // [B*N*N]

  dot_attn_wave_kernel<<<S / kWavesPerBlock, kThreads, 0, stream>>>(
      q, k, v, out, dist, N);
}

// Round 5
// 177.740 us; speedup vs baseline: 1.0985x; 1.0985x over previous
//
#include <hip/hip_runtime.h>

// DotAttentionLayer: q,k,v are [B,N] (B=16, N=4096). Head dim == 1, so
//   scores[b,i,j] = q[b,i]*k[b,j]/sqrt(4096)
//   dist = softmax_j(scores); out[b,i] = sum_j dist[b,i,j]*v[b,j]
// d_out = [ output (B*N f32) | distribution (B*N*N f32) ]  ~1.07 GB writes.
// One block per row (b,i); float4 index = t*256 + tid (coalesced full-line
// wave stores). R5 A/B: plain stores instead of nontemporal — the rocclr
// fill kernel hits 6.5+ TB/s with plain stores on this same buffer, while
// our nt stream implied only 5.7 TB/s.

typedef float f32x4 __attribute__((ext_vector_type(4)));

constexpr int kThreads = 256;
constexpr float kInvSqrtScale = 1.0f / 64.0f;  // 1/sqrt(4096)

__device__ __forceinline__ float wave_reduce_sum(float x) {
#pragma unroll
  for (int off = 32; off > 0; off >>= 1) x += __shfl_down(x, off, 64);
  return x;
}

__global__ __launch_bounds__(kThreads) void dot_attn_row_kernel(
    const float* __restrict__ q, const float* __restrict__ k,
    const float* __restrict__ v, float* __restrict__ out,
    float* __restrict__ dist, int N) {
  const int row = blockIdx.x;        // row = b*N + i
  const int b = row / N;
  const float a = q[row] * kInvSqrtScale;

  const f32x4* kb = reinterpret_cast<const f32x4*>(k) + (size_t)b * (N / 4);
  const f32x4* vb = reinterpret_cast<const f32x4*>(v) + (size_t)b * (N / 4);

  // N == 4096: 1024 float4 per row; 4 per thread at stride 256 (coalesced).
  f32x4 e[4];
  float s = 0.f, pv = 0.f;
#pragma unroll
  for (int t = 0; t < 4; ++t) {
    const int idx = t * kThreads + threadIdx.x;  // float4 index within row
    const f32x4 kk = kb[idx];
    const f32x4 vv = vb[idx];
    f32x4 ee;
    ee.x = __expf(a * kk.x);
    ee.y = __expf(a * kk.y);
    ee.z = __expf(a * kk.z);
    ee.w = __expf(a * kk.w);
    e[t] = ee;
    s  += (ee.x + ee.y) + (ee.z + ee.w);
    pv += (ee.x * vv.x + ee.y * vv.y) + (ee.z * vv.z + ee.w * vv.w);
  }

  // Block reduction: per-wave shuffle, then 4 partials through LDS.
  s = wave_reduce_sum(s);
  pv = wave_reduce_sum(pv);
  __shared__ float red_s[4];
  __shared__ float red_pv[4];
  const int lane = threadIdx.x & 63;
  const int wid = threadIdx.x >> 6;
  if (lane == 0) { red_s[wid] = s; red_pv[wid] = pv; }
  __syncthreads();
  const float stot = (red_s[0] + red_s[1]) + (red_s[2] + red_s[3]);
  const float rinv = 1.0f / stot;

  f32x4* drow = reinterpret_cast<f32x4*>(dist) + (size_t)row * (N / 4);
#pragma unroll
  for (int t = 0; t < 4; ++t) {
    const int idx = t * kThreads + threadIdx.x;
    const f32x4 ee = e[t];
    f32x4 dd;
    dd.x = ee.x * rinv;
    dd.y = ee.y * rinv;
    dd.z = ee.z * rinv;
    dd.w = ee.w * rinv;
    drow[idx] = dd;  // plain store: full-line wave stores, no RFO (fill-kernel datapoint)
  }

  if (threadIdx.x == 0) {
    const float pvtot = (red_pv[0] + red_pv[1]) + (red_pv[2] + red_pv[3]);
    out[row] = pvtot * rinv;
  }
}

extern "C" void kernel_launch(void* const* d_in, const int* in_sizes, int n_in,
                              void* d_out, int out_size, void* d_ws, size_t ws_size,
                              hipStream_t stream) {
  // setup_inputs dict order: query, value, key  (f32 each, [B,N])
  const float* q = (const float*)d_in[0];
  const float* v = (const float*)d_in[1];
  const float* k = (const float*)d_in[2];

  const int S = in_sizes[0];                    // B*N = 65536
  const int N = (int)((size_t)out_size / S) - 1;  // 4096
  float* out = (float*)d_out;                   // [B*N]
  float* dist = out + S;                        // [B*N*N]

  dot_attn_row_kernel<<<S, kThreads, 0, stream>>>(q, k, v, out, dist, N);
}